// Round 1
// baseline (6169.800 us; speedup 1.0000x reference)
//
#include <hip/hip_runtime.h>

// RGCN: N=100000 nodes, F=128, R=4 relations, E=1600000 edges, L=2 layers.
// Per layer: h[n,r,:] = mean_{e: dst=n, et=r} x[src[e]]   (scatter+atomics)
//            out = [h_0|h_1|h_2|h_3|x] @ [W_0;W_1;W_2;W_3;root] + bias, relu
#define N_NODES 100000
#define FDIM 128
#define RREL 4
#define NEDGE 1600000
#define KTOT (RREL * FDIM + FDIM) // 640

// ---------- scatter: sums[(dst*R+et)*F + f] += x[src][f]; cnt[dst*R+et] += 1 ----------
__global__ __launch_bounds__(256) void rgcn_scatter(
    const float* __restrict__ x,
    const int* __restrict__ src,
    const int* __restrict__ dst,
    const int* __restrict__ et,
    float* __restrict__ sums,
    float* __restrict__ cnt)
{
    int e = blockIdx.x * 8 + (threadIdx.x >> 5); // 8 edges per 256-thread block
    int lane = threadIdx.x & 31;                 // 32 lanes x float4 = 128 floats
    if (e >= NEDGE) return;
    int s = src[e];
    int d = dst[e];
    int t = et[e];
    const float4 v = ((const float4*)(x + (size_t)s * FDIM))[lane];
    float* base = sums + ((size_t)d * RREL + t) * FDIM + lane * 4;
    atomicAdd(base + 0, v.x);
    atomicAdd(base + 1, v.y);
    atomicAdd(base + 2, v.z);
    atomicAdd(base + 3, v.w);
    if (lane == 0) atomicAdd(cnt + (size_t)d * RREL + t, 1.0f);
}

// ---------- fused mean + GEMM(K=640) + bias + relu ----------
// Block: 32 rows of N x all 128 output cols. 256 threads, 4x4 outputs/thread.
__global__ __launch_bounds__(256) void rgcn_transform(
    const float* __restrict__ x,    // [N,128] current features
    const float* __restrict__ sums, // [N,512] (= [N,R,F])
    const float* __restrict__ cnt,  // [N,4]
    const float* __restrict__ W,    // [4,128,128] this layer (k=r*128+f -> row k)
    const float* __restrict__ root, // [128,128]
    const float* __restrict__ bias, // [128]
    float* __restrict__ out)        // [N,128]
{
    __shared__ __align__(16) float At[32][36]; // transposed A chunk: At[k][row], pad 36 keeps 16B align
    __shared__ __align__(16) float Bt[32][128];
    __shared__ float invc[128]; // 32 rows x 4 rel

    int tid = threadIdx.x;
    int n0 = blockIdx.x * 32;

    if (tid < 128) {
        float c = cnt[(size_t)n0 * 4 + tid];
        invc[tid] = 1.0f / fmaxf(c, 1.0f);
    }
    __syncthreads();

    int tx = tid & 31; // col group: cols tx*4 .. +3
    int ty = tid >> 5; // row group: rows ty*4 .. +3
    float acc[4][4] = {};

    // A staging: thread loads one float4 (row a_row, k-quad a_kq)
    int a_row = tid >> 3;       // 0..31
    int a_kq = (tid & 7) * 4;   // 0,4,..,28
    int n_g = n0 + a_row;

    for (int kb = 0; kb < KTOT; kb += 32) {
        // ---- stage A (apply 1/max(cnt,1) for the sums region) ----
        {
            int k = kb + a_kq;
            float4 v;
            if (k < 512) {
                v = *(const float4*)(sums + (size_t)n_g * 512 + k);
                float s = invc[a_row * 4 + (k >> 7)]; // r = k/128, constant across the quad
                v.x *= s; v.y *= s; v.z *= s; v.w *= s;
            } else {
                v = *(const float4*)(x + (size_t)n_g * 128 + (k - 512));
            }
            At[a_kq + 0][a_row] = v.x;
            At[a_kq + 1][a_row] = v.y;
            At[a_kq + 2][a_row] = v.z;
            At[a_kq + 3][a_row] = v.w;
        }
        // ---- stage B: 32 rows x 128 cols, 4 float4 per thread ----
        #pragma unroll
        for (int i = 0; i < 4; ++i) {
            int fid = tid + i * 256; // float4 id 0..1023
            int k = fid >> 5;        // 0..31
            int c4 = (fid & 31) * 4; // col
            int kg = kb + k;
            const float* srcp = (kg < 512) ? (W + (size_t)kg * 128 + c4)
                                           : (root + (size_t)(kg - 512) * 128 + c4);
            *(float4*)&Bt[k][c4] = *(const float4*)srcp;
        }
        __syncthreads();
        #pragma unroll
        for (int k = 0; k < 32; ++k) {
            float4 a4 = *(const float4*)&At[k][ty * 4];
            float4 b4 = *(const float4*)&Bt[k][tx * 4];
            float av[4] = {a4.x, a4.y, a4.z, a4.w};
            float bv[4] = {b4.x, b4.y, b4.z, b4.w};
            #pragma unroll
            for (int i = 0; i < 4; ++i)
                #pragma unroll
                for (int j = 0; j < 4; ++j)
                    acc[i][j] = fmaf(av[i], bv[j], acc[i][j]);
        }
        __syncthreads();
    }

    // ---- epilogue: +bias, relu, store ----
    float4 bb = *(const float4*)(bias + tx * 4);
    #pragma unroll
    for (int i = 0; i < 4; ++i) {
        int n = n0 + ty * 4 + i;
        float4 o;
        o.x = fmaxf(acc[i][0] + bb.x, 0.0f);
        o.y = fmaxf(acc[i][1] + bb.y, 0.0f);
        o.z = fmaxf(acc[i][2] + bb.z, 0.0f);
        o.w = fmaxf(acc[i][3] + bb.w, 0.0f);
        *(float4*)(out + (size_t)n * FDIM + tx * 4) = o;
    }
}

extern "C" void kernel_launch(void* const* d_in, const int* in_sizes, int n_in,
                              void* d_out, int out_size, void* d_ws, size_t ws_size,
                              hipStream_t stream) {
    const float* x       = (const float*)d_in[0];
    const int* edge_index = (const int*)d_in[1]; // [2,E]
    const int* edge_type  = (const int*)d_in[2]; // [E]
    const float* weights  = (const float*)d_in[3]; // [L,R,F,F]
    const float* roots    = (const float*)d_in[4]; // [L,F,F]
    const float* biases   = (const float*)d_in[5]; // [L,F]
    float* out = (float*)d_out;

    float* sums = (float*)d_ws;                       // N*512 floats
    float* cnt  = sums + (size_t)N_NODES * RREL * FDIM; // N*4 floats

    const int* src = edge_index;
    const int* dst = edge_index + NEDGE;

    for (int l = 0; l < 2; ++l) {
        const float* xin = (l == 0) ? x : out;
        // zero sums + cnt (contiguous): N*(512+4) floats
        hipMemsetAsync(d_ws, 0, (size_t)N_NODES * (RREL * FDIM + RREL) * sizeof(float), stream);
        rgcn_scatter<<<NEDGE / 8, 256, 0, stream>>>(xin, src, dst, edge_type, sums, cnt);
        rgcn_transform<<<N_NODES / 32, 256, 0, stream>>>(
            xin, sums, cnt,
            weights + (size_t)l * RREL * FDIM * FDIM,
            roots + (size_t)l * FDIM * FDIM,
            biases + (size_t)l * FDIM,
            out);
    }
}

// Round 2
// 1096.554 us; speedup vs baseline: 5.6265x; 5.6265x over previous
//
#include <hip/hip_runtime.h>

// RGCN: N=100000, F=128, R=4, E=1600000, L=2.
// Per layer: mean[n,r,:] = mean_{e: dst=n, et=r} x[src[e]]
//            out = [mean_0..mean_3 | x] @ [W_0;..;W_3;root] + bias, relu
//
// R2: replace fp32 payload atomics (205M/layer, 74G/s-bound) with a CSR built
// once per call (int atomics only: 3.2M total), then deterministic per-segment
// gather-reduce with plain loads/stores.
#define N_NODES 100000
#define FDIM 128
#define RREL 4
#define NEDGE 1600000
#define NSEG (N_NODES * RREL)      // 400000 (dst,rel) segments
#define KTOT (RREL * FDIM + FDIM)  // 640
#define SCAN_NB ((NSEG + 1023) / 1024) // 391

// ---------- 1. count edges per segment ----------
__global__ __launch_bounds__(256) void count_edges(
    const int* __restrict__ dst, const int* __restrict__ et,
    int* __restrict__ counts)
{
    int e = blockIdx.x * 256 + threadIdx.x;
    if (e < NEDGE) atomicAdd(&counts[dst[e] * RREL + et[e]], 1);
}

// ---------- 2a. per-block exclusive scan (1024 elems/block) ----------
__global__ __launch_bounds__(256) void scan_blocks(
    const int* __restrict__ counts, int* __restrict__ cursor,
    int* __restrict__ blockSums)
{
    __shared__ int waveTot[4];
    int base = blockIdx.x * 1024 + threadIdx.x * 4;
    int v[4];
    #pragma unroll
    for (int i = 0; i < 4; ++i) {
        int idx = base + i;
        v[i] = (idx < NSEG) ? counts[idx] : 0;
    }
    int tsum = v[0] + v[1] + v[2] + v[3];
    int lane = threadIdx.x & 63;
    int wave = threadIdx.x >> 6;
    int inc = tsum; // inclusive scan of thread sums across the wave
    #pragma unroll
    for (int d = 1; d < 64; d <<= 1) {
        int o = __shfl_up(inc, d, 64);
        if (lane >= d) inc += o;
    }
    if (lane == 63) waveTot[wave] = inc;
    __syncthreads();
    int wbase = 0;
    for (int w = 0; w < wave; ++w) wbase += waveTot[w];
    int run = wbase + inc - tsum; // exclusive prefix for this thread
    #pragma unroll
    for (int i = 0; i < 4; ++i) {
        int idx = base + i;
        if (idx < NSEG) cursor[idx] = run;
        run += v[i];
    }
    if (threadIdx.x == 255) blockSums[blockIdx.x] = wbase + inc; // block total
}

// ---------- 2b. scan the 391 block totals (single block) ----------
__global__ __launch_bounds__(512) void scan_partials(int* __restrict__ blockSums)
{
    __shared__ int sm[512];
    int t = threadIdx.x;
    int v = (t < SCAN_NB) ? blockSums[t] : 0;
    sm[t] = v;
    __syncthreads();
    for (int d = 1; d < 512; d <<= 1) {
        int o = (t >= d) ? sm[t - d] : 0;
        __syncthreads();
        sm[t] += o;
        __syncthreads();
    }
    if (t < SCAN_NB) blockSums[t] = sm[t] - v; // exclusive
}

// ---------- 2c. add block bases ----------
__global__ __launch_bounds__(256) void scan_add(
    int* __restrict__ cursor, const int* __restrict__ blockSums)
{
    int base = blockIdx.x * 1024 + threadIdx.x * 4;
    int add = blockSums[blockIdx.x];
    #pragma unroll
    for (int i = 0; i < 4; ++i)
        if (base + i < NSEG) cursor[base + i] += add;
}

// ---------- 3. place src node ids into segment-sorted order ----------
__global__ __launch_bounds__(256) void fill_edges(
    const int* __restrict__ src, const int* __restrict__ dst,
    const int* __restrict__ et, int* __restrict__ cursor,
    int* __restrict__ esrc)
{
    int e = blockIdx.x * 256 + threadIdx.x;
    if (e < NEDGE) {
        int seg = dst[e] * RREL + et[e];
        int pos = atomicAdd(&cursor[seg], 1);
        esrc[pos] = src[e];
    }
}

// ---------- 4. per-segment gather-reduce: mean[seg][:] ----------
// One 64-lane wave per segment (float2/lane), 4 segments per 256-thread block.
// After fill, cursor[seg] == segment end; start = end - counts[seg].
__global__ __launch_bounds__(256) void rgcn_aggregate(
    const float* __restrict__ x, const int* __restrict__ esrc,
    const int* __restrict__ cursor, const int* __restrict__ counts,
    float* __restrict__ mean)
{
    int seg = blockIdx.x * 4 + (threadIdx.x >> 6);
    int lane = threadIdx.x & 63;
    int end = cursor[seg];
    int c = counts[seg];
    int j = end - c;
    float2 acc = make_float2(0.0f, 0.0f);
    // 2-wide unroll: two independent gathers in flight
    for (; j + 1 < end; j += 2) {
        int s0 = esrc[j], s1 = esrc[j + 1];
        float2 v0 = ((const float2*)(x + (size_t)s0 * FDIM))[lane];
        float2 v1 = ((const float2*)(x + (size_t)s1 * FDIM))[lane];
        acc.x += v0.x + v1.x;
        acc.y += v0.y + v1.y;
    }
    if (j < end) {
        int s = esrc[j];
        float2 v = ((const float2*)(x + (size_t)s * FDIM))[lane];
        acc.x += v.x;
        acc.y += v.y;
    }
    float inv = 1.0f / fmaxf((float)c, 1.0f);
    ((float2*)(mean + (size_t)seg * FDIM))[lane] = make_float2(acc.x * inv, acc.y * inv);
}

// ---------- 5. fused GEMM(K=640) + bias + relu ----------
// Block: 32 rows x 128 cols, 256 threads, 4x4 outputs/thread.
__global__ __launch_bounds__(256) void rgcn_transform(
    const float* __restrict__ x,    // [N,128]
    const float* __restrict__ mean, // [N,512] (= [N,R,F], already mean)
    const float* __restrict__ W,    // [4,128,128]
    const float* __restrict__ root, // [128,128]
    const float* __restrict__ bias, // [128]
    float* __restrict__ out)        // [N,128]
{
    __shared__ __align__(16) float At[32][36];
    __shared__ __align__(16) float Bt[32][128];

    int tid = threadIdx.x;
    int n0 = blockIdx.x * 32;

    int tx = tid & 31;
    int ty = tid >> 5;
    float acc[4][4] = {};

    int a_row = tid >> 3;
    int a_kq = (tid & 7) * 4;
    int n_g = n0 + a_row;

    for (int kb = 0; kb < KTOT; kb += 32) {
        {
            int k = kb + a_kq;
            float4 v;
            if (k < 512) {
                v = *(const float4*)(mean + (size_t)n_g * 512 + k);
            } else {
                v = *(const float4*)(x + (size_t)n_g * 128 + (k - 512));
            }
            At[a_kq + 0][a_row] = v.x;
            At[a_kq + 1][a_row] = v.y;
            At[a_kq + 2][a_row] = v.z;
            At[a_kq + 3][a_row] = v.w;
        }
        #pragma unroll
        for (int i = 0; i < 4; ++i) {
            int fid = tid + i * 256;
            int k = fid >> 5;
            int c4 = (fid & 31) * 4;
            int kg = kb + k;
            const float* srcp = (kg < 512) ? (W + (size_t)kg * 128 + c4)
                                           : (root + (size_t)(kg - 512) * 128 + c4);
            *(float4*)&Bt[k][c4] = *(const float4*)srcp;
        }
        __syncthreads();
        #pragma unroll
        for (int k = 0; k < 32; ++k) {
            float4 a4 = *(const float4*)&At[k][ty * 4];
            float4 b4 = *(const float4*)&Bt[k][tx * 4];
            float av[4] = {a4.x, a4.y, a4.z, a4.w};
            float bv[4] = {b4.x, b4.y, b4.z, b4.w};
            #pragma unroll
            for (int i = 0; i < 4; ++i)
                #pragma unroll
                for (int j = 0; j < 4; ++j)
                    acc[i][j] = fmaf(av[i], bv[j], acc[i][j]);
        }
        __syncthreads();
    }

    float4 bb = *(const float4*)(bias + tx * 4);
    #pragma unroll
    for (int i = 0; i < 4; ++i) {
        int n = n0 + ty * 4 + i;
        float4 o;
        o.x = fmaxf(acc[i][0] + bb.x, 0.0f);
        o.y = fmaxf(acc[i][1] + bb.y, 0.0f);
        o.z = fmaxf(acc[i][2] + bb.z, 0.0f);
        o.w = fmaxf(acc[i][3] + bb.w, 0.0f);
        *(float4*)(out + (size_t)n * FDIM + tx * 4) = o;
    }
}

extern "C" void kernel_launch(void* const* d_in, const int* in_sizes, int n_in,
                              void* d_out, int out_size, void* d_ws, size_t ws_size,
                              hipStream_t stream) {
    const float* x        = (const float*)d_in[0];
    const int* edge_index = (const int*)d_in[1]; // [2,E]
    const int* edge_type  = (const int*)d_in[2]; // [E]
    const float* weights  = (const float*)d_in[3]; // [L,R,F,F]
    const float* roots    = (const float*)d_in[4]; // [L,F,F]
    const float* biases   = (const float*)d_in[5]; // [L,F]
    float* out = (float*)d_out;

    // workspace layout (16B-aligned head first)
    float* mean   = (float*)d_ws;                         // N*512 floats = 204.8 MB
    int*   esrc   = (int*)(mean + (size_t)NSEG * FDIM);   // E ints = 6.4 MB
    int*   counts = esrc + NEDGE;                         // NSEG ints
    int*   cursor = counts + NSEG;                        // NSEG ints
    int*   blockSums = cursor + NSEG;                     // 512 ints

    const int* src = edge_index;
    const int* dst = edge_index + NEDGE;

    // ---- build CSR once (edges are layer-invariant) ----
    hipMemsetAsync(counts, 0, NSEG * sizeof(int), stream);
    count_edges<<<NEDGE / 256, 256, 0, stream>>>(dst, edge_type, counts);
    scan_blocks<<<SCAN_NB, 256, 0, stream>>>(counts, cursor, blockSums);
    scan_partials<<<1, 512, 0, stream>>>(blockSums);
    scan_add<<<SCAN_NB, 256, 0, stream>>>(cursor, blockSums);
    fill_edges<<<NEDGE / 256, 256, 0, stream>>>(src, dst, edge_type, cursor, esrc);

    for (int l = 0; l < 2; ++l) {
        const float* xin = (l == 0) ? x : out;
        rgcn_aggregate<<<NSEG / 4, 256, 0, stream>>>(xin, esrc, cursor, counts, mean);
        rgcn_transform<<<N_NODES / 32, 256, 0, stream>>>(
            xin, mean,
            weights + (size_t)l * RREL * FDIM * FDIM,
            roots + (size_t)l * FDIM * FDIM,
            biases + (size_t)l * FDIM,
            out);
    }
}

// Round 4
// 856.645 us; speedup vs baseline: 7.2023x; 1.2801x over previous
//
#include <hip/hip_runtime.h>
#include <hip/hip_bf16.h>

// RGCN: N=100000, F=128, R=4, E=1600000, L=2.
// R4 = R2's proven-passing skeleton (f32 CSR aggregate, f32 mean, d_out
// activation ping) with ONLY the transform swapped to bf16 MFMA
// (in-kernel f32->bf16 A conversion, pre-swizzled B fragments, no LDS).
#define N_NODES 100000
#define FDIM 128
#define RREL 4
#define NEDGE 1600000
#define NSEG (N_NODES * RREL)          // 400000
#define SCAN_NB ((NSEG + 1023) / 1024) // 391
#define KB_TOT 20                      // 640 / 32 k-steps
#define BSW_PER_LAYER (KB_TOT * 8 * 64 * 8) // 81920 bf16 elems = 160 KB

typedef __attribute__((ext_vector_type(8))) short bfrag; // 8 bf16 (4 VGPR)
typedef __attribute__((ext_vector_type(4))) float ffrag; // 4 f32 acc

__device__ __forceinline__ unsigned short f2bf(float f) {
    unsigned u = __float_as_uint(f);
    u += 0x7fffu + ((u >> 16) & 1u); // RNE
    return (unsigned short)(u >> 16);
}

// pack 8 consecutive f32 -> bf16 A-fragment (RNE via v_cvt_pk_bf16_f32)
__device__ __forceinline__ bfrag cvt8(const float* __restrict__ p) {
    float4 a = *(const float4*)p;
    float4 b = *(const float4*)(p + 4);
    union { bfrag v; __hip_bfloat162 h[4]; } u;
    u.h[0] = __float22bfloat162_rn(make_float2(a.x, a.y));
    u.h[1] = __float22bfloat162_rn(make_float2(a.z, a.w));
    u.h[2] = __float22bfloat162_rn(make_float2(b.x, b.y));
    u.h[3] = __float22bfloat162_rn(make_float2(b.z, b.w));
    return u.v;
}

// ---------- pre-swizzle weights into MFMA B-fragment order ----------
// Bsw[layer][kb][ct][lane][j] = B[k = kb*32 + (lane>>4)*8 + j][n = ct*16 + (lane&15)]
// B row k<512 -> W[layer][k*128+n], else root[layer][(k-512)*128+n].
__global__ __launch_bounds__(256) void prep_weights(
    const float* __restrict__ W,    // [L,4,128,128]
    const float* __restrict__ root, // [L,128,128]
    unsigned short* __restrict__ Bsw)
{
    int idx = blockIdx.x * 256 + threadIdx.x; // 0 .. 2*81920-1
    int layer = idx / BSW_PER_LAYER;
    int rem = idx % BSW_PER_LAYER;
    int kb = rem / 4096;
    int rem2 = rem % 4096;
    int ct = rem2 / 512;
    int rem3 = rem2 % 512;
    int lane = rem3 / 8;
    int j = rem3 % 8;
    int k = kb * 32 + (lane >> 4) * 8 + j;
    int n = ct * 16 + (lane & 15);
    float v;
    if (k < 512) v = W[(size_t)layer * 4 * 128 * 128 + (size_t)k * 128 + n];
    else         v = root[(size_t)layer * 128 * 128 + (size_t)(k - 512) * 128 + n];
    Bsw[idx] = f2bf(v);
}

// ---------- CSR build (verbatim from R2, which passed all tripwires) ----------
__global__ __launch_bounds__(256) void count_edges(
    const int* __restrict__ dst, const int* __restrict__ et,
    int* __restrict__ counts)
{
    int e = blockIdx.x * 256 + threadIdx.x;
    if (e < NEDGE) atomicAdd(&counts[dst[e] * RREL + et[e]], 1);
}

__global__ __launch_bounds__(256) void scan_blocks(
    const int* __restrict__ counts, int* __restrict__ cursor,
    int* __restrict__ blockSums)
{
    __shared__ int waveTot[4];
    int base = blockIdx.x * 1024 + threadIdx.x * 4;
    int v[4];
    #pragma unroll
    for (int i = 0; i < 4; ++i) {
        int idx = base + i;
        v[i] = (idx < NSEG) ? counts[idx] : 0;
    }
    int tsum = v[0] + v[1] + v[2] + v[3];
    int lane = threadIdx.x & 63;
    int wave = threadIdx.x >> 6;
    int inc = tsum;
    #pragma unroll
    for (int d = 1; d < 64; d <<= 1) {
        int o = __shfl_up(inc, d, 64);
        if (lane >= d) inc += o;
    }
    if (lane == 63) waveTot[wave] = inc;
    __syncthreads();
    int wbase = 0;
    for (int w = 0; w < wave; ++w) wbase += waveTot[w];
    int run = wbase + inc - tsum;
    #pragma unroll
    for (int i = 0; i < 4; ++i) {
        int idx = base + i;
        if (idx < NSEG) cursor[idx] = run;
        run += v[i];
    }
    if (threadIdx.x == 255) blockSums[blockIdx.x] = wbase + inc;
}

__global__ __launch_bounds__(512) void scan_partials(int* __restrict__ blockSums)
{
    __shared__ int sm[512];
    int t = threadIdx.x;
    int v = (t < SCAN_NB) ? blockSums[t] : 0;
    sm[t] = v;
    __syncthreads();
    for (int d = 1; d < 512; d <<= 1) {
        int o = (t >= d) ? sm[t - d] : 0;
        __syncthreads();
        sm[t] += o;
        __syncthreads();
    }
    if (t < SCAN_NB) blockSums[t] = sm[t] - v;
}

__global__ __launch_bounds__(256) void scan_add(
    int* __restrict__ cursor, const int* __restrict__ blockSums)
{
    int base = blockIdx.x * 1024 + threadIdx.x * 4;
    int add = blockSums[blockIdx.x];
    #pragma unroll
    for (int i = 0; i < 4; ++i)
        if (base + i < NSEG) cursor[base + i] += add;
}

__global__ __launch_bounds__(256) void fill_edges(
    const int* __restrict__ src, const int* __restrict__ dst,
    const int* __restrict__ et, int* __restrict__ cursor,
    int* __restrict__ esrc)
{
    int e = blockIdx.x * 256 + threadIdx.x;
    if (e < NEDGE) {
        int seg = dst[e] * RREL + et[e];
        int pos = atomicAdd(&cursor[seg], 1);
        esrc[pos] = src[e];
    }
}

// ---------- per-segment gather-reduce (verbatim from R2) ----------
__global__ __launch_bounds__(256) void rgcn_aggregate(
    const float* __restrict__ x, const int* __restrict__ esrc,
    const int* __restrict__ cursor, const int* __restrict__ counts,
    float* __restrict__ mean)
{
    int seg = blockIdx.x * 4 + (threadIdx.x >> 6);
    int lane = threadIdx.x & 63;
    int end = cursor[seg];
    int c = counts[seg];
    int j = end - c;
    float2 acc = make_float2(0.0f, 0.0f);
    for (; j + 1 < end; j += 2) {
        int s0 = esrc[j], s1 = esrc[j + 1];
        float2 v0 = ((const float2*)(x + (size_t)s0 * FDIM))[lane];
        float2 v1 = ((const float2*)(x + (size_t)s1 * FDIM))[lane];
        acc.x += v0.x + v1.x;
        acc.y += v0.y + v1.y;
    }
    if (j < end) {
        int s = esrc[j];
        float2 v = ((const float2*)(x + (size_t)s * FDIM))[lane];
        acc.x += v.x;
        acc.y += v.y;
    }
    float inv = 1.0f / fmaxf((float)c, 1.0f);
    ((float2*)(mean + (size_t)seg * FDIM))[lane] = make_float2(acc.x * inv, acc.y * inv);
}

// ---------- MFMA transform: out = [mean|x] @ Bsw + bias, relu ----------
// One 64-lane wave per block; block covers 32 rows x 128 cols. Grid 3125 exact.
// A frags: f32 loads + packed cvt to bf16 in-register; B frags: single 16B
// loads from pre-swizzled L2-resident Bsw. No LDS, no barriers.
// Reads of x rows are confined to this block's own 32 rows, so x may alias out
// (same guarantee the R2 kernel relied on).
__global__ __launch_bounds__(64) void rgcn_transform(
    const float* __restrict__ x,    // [N,128]
    const float* __restrict__ mean, // [N,512]
    const unsigned short* __restrict__ Bsw, // this layer's [20][8][64][8]
    const float* __restrict__ bias, // [128]
    float* __restrict__ out)        // [N,128]
{
    int lane = threadIdx.x;
    int quad = lane >> 4, rlo = lane & 15;
    int n0 = blockIdx.x * 32;
    int r0 = n0 + rlo;
    int r1 = n0 + 16 + rlo;

    const float* m0 = mean + (size_t)r0 * 512 + quad * 8;
    const float* m1 = mean + (size_t)r1 * 512 + quad * 8;
    const float* x0 = x + (size_t)r0 * FDIM + quad * 8;
    const float* x1 = x + (size_t)r1 * FDIM + quad * 8;
    const bfrag* bp = (const bfrag*)Bsw + lane;

    ffrag acc[2][8] = {};

    // k = 0..511 : mean part
    #pragma unroll 4
    for (int kb = 0; kb < 16; ++kb) {
        bfrag a0 = cvt8(m0 + kb * 32);
        bfrag a1 = cvt8(m1 + kb * 32);
        #pragma unroll
        for (int ct = 0; ct < 8; ++ct) {
            bfrag b = bp[(kb * 8 + ct) * 64];
            acc[0][ct] = __builtin_amdgcn_mfma_f32_16x16x32_bf16(a0, b, acc[0][ct], 0, 0, 0);
            acc[1][ct] = __builtin_amdgcn_mfma_f32_16x16x32_bf16(a1, b, acc[1][ct], 0, 0, 0);
        }
    }
    // k = 512..639 : x part
    #pragma unroll
    for (int kb = 0; kb < 4; ++kb) {
        bfrag a0 = cvt8(x0 + kb * 32);
        bfrag a1 = cvt8(x1 + kb * 32);
        #pragma unroll
        for (int ct = 0; ct < 8; ++ct) {
            bfrag b = bp[((16 + kb) * 8 + ct) * 64];
            acc[0][ct] = __builtin_amdgcn_mfma_f32_16x16x32_bf16(a0, b, acc[0][ct], 0, 0, 0);
            acc[1][ct] = __builtin_amdgcn_mfma_f32_16x16x32_bf16(a1, b, acc[1][ct], 0, 0, 0);
        }
    }

    // epilogue: D layout col = ct*16 + rlo, row = n0 + rt*16 + quad*4 + reg
    float bcol[8];
    #pragma unroll
    for (int ct = 0; ct < 8; ++ct) bcol[ct] = bias[ct * 16 + rlo];

    #pragma unroll
    for (int rt = 0; rt < 2; ++rt) {
        int rbase = n0 + rt * 16 + quad * 4;
        #pragma unroll
        for (int i = 0; i < 4; ++i) {
            int r = rbase + i;
            #pragma unroll
            for (int ct = 0; ct < 8; ++ct) {
                float v = fmaxf(acc[rt][ct][i] + bcol[ct], 0.0f);
                out[(size_t)r * FDIM + ct * 16 + rlo] = v;
            }
        }
    }
}

extern "C" void kernel_launch(void* const* d_in, const int* in_sizes, int n_in,
                              void* d_out, int out_size, void* d_ws, size_t ws_size,
                              hipStream_t stream) {
    const float* x        = (const float*)d_in[0];
    const int* edge_index = (const int*)d_in[1]; // [2,E]
    const int* edge_type  = (const int*)d_in[2]; // [E]
    const float* weights  = (const float*)d_in[3]; // [L,R,F,F]
    const float* roots    = (const float*)d_in[4]; // [L,F,F]
    const float* biases   = (const float*)d_in[5]; // [L,F]
    float* out = (float*)d_out;

    // workspace layout (identical to R2 + Bsw appended)
    float* mean   = (float*)d_ws;                         // N*512 floats = 204.8 MB
    int*   esrc   = (int*)(mean + (size_t)NSEG * FDIM);   // E ints
    int*   counts = esrc + NEDGE;                         // NSEG
    int*   cursor = counts + NSEG;                        // NSEG
    int*   blockSums = cursor + NSEG;                     // 512
    unsigned short* Bsw = (unsigned short*)(blockSums + 512); // 2*81920 bf16

    const int* src = edge_index;
    const int* dst = edge_index + NEDGE;

    // prep: weight swizzle + CSR (edges layer-invariant)
    prep_weights<<<2 * BSW_PER_LAYER / 256, 256, 0, stream>>>(weights, roots, Bsw);
    hipMemsetAsync(counts, 0, NSEG * sizeof(int), stream);
    count_edges<<<NEDGE / 256, 256, 0, stream>>>(dst, edge_type, counts);
    scan_blocks<<<SCAN_NB, 256, 0, stream>>>(counts, cursor, blockSums);
    scan_partials<<<1, 512, 0, stream>>>(blockSums);
    scan_add<<<SCAN_NB, 256, 0, stream>>>(cursor, blockSums);
    fill_edges<<<NEDGE / 256, 256, 0, stream>>>(src, dst, edge_type, cursor, esrc);

    for (int l = 0; l < 2; ++l) {
        const float* xin = (l == 0) ? x : out;
        rgcn_aggregate<<<NSEG / 4, 256, 0, stream>>>(xin, esrc, cursor, counts, mean);
        rgcn_transform<<<N_NODES / 32, 64, 0, stream>>>(
            xin, mean, Bsw + (size_t)l * BSW_PER_LAYER,
            biases + (size_t)l * FDIM, out);
    }
}

// Round 5
// 749.202 us; speedup vs baseline: 8.2352x; 1.1434x over previous
//
#include <hip/hip_runtime.h>
#include <hip/hip_bf16.h>

// RGCN: N=100000, F=128, R=4, E=1600000, L=2.
// R5 = R4 skeleton with bf16 gather path: bf16 x sidecar, bf16 mean,
// transform reads bf16 mean frags directly. Single-delta experiment vs R4.
#define N_NODES 100000
#define FDIM 128
#define RREL 4
#define NEDGE 1600000
#define NSEG (N_NODES * RREL)          // 400000
#define SCAN_NB ((NSEG + 1023) / 1024) // 391
#define KB_TOT 20                      // 640 / 32 k-steps
#define BSW_PER_LAYER (KB_TOT * 8 * 64 * 8) // 81920 bf16 elems = 160 KB

typedef __attribute__((ext_vector_type(8))) short bfrag; // 8 bf16 (4 VGPR)
typedef __attribute__((ext_vector_type(4))) float ffrag; // 4 f32 acc

__device__ __forceinline__ unsigned short f2bf(float f) {
    unsigned u = __float_as_uint(f);
    u += 0x7fffu + ((u >> 16) & 1u); // RNE
    return (unsigned short)(u >> 16);
}
__device__ __forceinline__ float bf_lo(unsigned u) { return __uint_as_float(u << 16); }
__device__ __forceinline__ float bf_hi(unsigned u) { return __uint_as_float(u & 0xffff0000u); }

// pack 8 consecutive f32 -> bf16 A-fragment (RNE via v_cvt_pk_bf16_f32)
__device__ __forceinline__ bfrag cvt8(const float* __restrict__ p) {
    float4 a = *(const float4*)p;
    float4 b = *(const float4*)(p + 4);
    union { bfrag v; __hip_bfloat162 h[4]; } u;
    u.h[0] = __float22bfloat162_rn(make_float2(a.x, a.y));
    u.h[1] = __float22bfloat162_rn(make_float2(a.z, a.w));
    u.h[2] = __float22bfloat162_rn(make_float2(b.x, b.y));
    u.h[3] = __float22bfloat162_rn(make_float2(b.z, b.w));
    return u.v;
}

// ---------- cast x (f32) -> bf16 sidecar ----------
__global__ __launch_bounds__(256) void cast_x(
    const float* __restrict__ x, unsigned short* __restrict__ xb)
{
    int i = blockIdx.x * 256 + threadIdx.x; // one float4 per thread
    float4 v = ((const float4*)x)[i];
    ushort4 o = { f2bf(v.x), f2bf(v.y), f2bf(v.z), f2bf(v.w) };
    ((ushort4*)xb)[i] = o;
}

// ---------- pre-swizzle weights into MFMA B-fragment order ----------
// Bsw[layer][kb][ct][lane][j] = B[k = kb*32 + (lane>>4)*8 + j][n = ct*16 + (lane&15)]
__global__ __launch_bounds__(256) void prep_weights(
    const float* __restrict__ W,    // [L,4,128,128]
    const float* __restrict__ root, // [L,128,128]
    unsigned short* __restrict__ Bsw)
{
    int idx = blockIdx.x * 256 + threadIdx.x;
    int layer = idx / BSW_PER_LAYER;
    int rem = idx % BSW_PER_LAYER;
    int kb = rem / 4096;
    int rem2 = rem % 4096;
    int ct = rem2 / 512;
    int rem3 = rem2 % 512;
    int lane = rem3 / 8;
    int j = rem3 % 8;
    int k = kb * 32 + (lane >> 4) * 8 + j;
    int n = ct * 16 + (lane & 15);
    float v;
    if (k < 512) v = W[(size_t)layer * 4 * 128 * 128 + (size_t)k * 128 + n];
    else         v = root[(size_t)layer * 128 * 128 + (size_t)(k - 512) * 128 + n];
    Bsw[idx] = f2bf(v);
}

// ---------- CSR build (verbatim from R2/R4) ----------
__global__ __launch_bounds__(256) void count_edges(
    const int* __restrict__ dst, const int* __restrict__ et,
    int* __restrict__ counts)
{
    int e = blockIdx.x * 256 + threadIdx.x;
    if (e < NEDGE) atomicAdd(&counts[dst[e] * RREL + et[e]], 1);
}

__global__ __launch_bounds__(256) void scan_blocks(
    const int* __restrict__ counts, int* __restrict__ cursor,
    int* __restrict__ blockSums)
{
    __shared__ int waveTot[4];
    int base = blockIdx.x * 1024 + threadIdx.x * 4;
    int v[4];
    #pragma unroll
    for (int i = 0; i < 4; ++i) {
        int idx = base + i;
        v[i] = (idx < NSEG) ? counts[idx] : 0;
    }
    int tsum = v[0] + v[1] + v[2] + v[3];
    int lane = threadIdx.x & 63;
    int wave = threadIdx.x >> 6;
    int inc = tsum;
    #pragma unroll
    for (int d = 1; d < 64; d <<= 1) {
        int o = __shfl_up(inc, d, 64);
        if (lane >= d) inc += o;
    }
    if (lane == 63) waveTot[wave] = inc;
    __syncthreads();
    int wbase = 0;
    for (int w = 0; w < wave; ++w) wbase += waveTot[w];
    int run = wbase + inc - tsum;
    #pragma unroll
    for (int i = 0; i < 4; ++i) {
        int idx = base + i;
        if (idx < NSEG) cursor[idx] = run;
        run += v[i];
    }
    if (threadIdx.x == 255) blockSums[blockIdx.x] = wbase + inc;
}

__global__ __launch_bounds__(512) void scan_partials(int* __restrict__ blockSums)
{
    __shared__ int sm[512];
    int t = threadIdx.x;
    int v = (t < SCAN_NB) ? blockSums[t] : 0;
    sm[t] = v;
    __syncthreads();
    for (int d = 1; d < 512; d <<= 1) {
        int o = (t >= d) ? sm[t - d] : 0;
        __syncthreads();
        sm[t] += o;
        __syncthreads();
    }
    if (t < SCAN_NB) blockSums[t] = sm[t] - v;
}

__global__ __launch_bounds__(256) void scan_add(
    int* __restrict__ cursor, const int* __restrict__ blockSums)
{
    int base = blockIdx.x * 1024 + threadIdx.x * 4;
    int add = blockSums[blockIdx.x];
    #pragma unroll
    for (int i = 0; i < 4; ++i)
        if (base + i < NSEG) cursor[base + i] += add;
}

__global__ __launch_bounds__(256) void fill_edges(
    const int* __restrict__ src, const int* __restrict__ dst,
    const int* __restrict__ et, int* __restrict__ cursor,
    int* __restrict__ esrc)
{
    int e = blockIdx.x * 256 + threadIdx.x;
    if (e < NEDGE) {
        int seg = dst[e] * RREL + et[e];
        int pos = atomicAdd(&cursor[seg], 1);
        esrc[pos] = src[e];
    }
}

// ---------- per-segment gather-reduce (bf16 in, bf16 out, f32 accum) ----------
// One 64-lane wave per segment: lane handles one bf16x2 dword of the row.
__global__ __launch_bounds__(256) void rgcn_aggregate(
    const unsigned short* __restrict__ xb, const int* __restrict__ esrc,
    const int* __restrict__ cursor, const int* __restrict__ counts,
    unsigned short* __restrict__ meanb)
{
    int seg = blockIdx.x * 4 + (threadIdx.x >> 6);
    int lane = threadIdx.x & 63;
    int end = cursor[seg];
    int c = counts[seg];
    int j = end - c;
    float ax = 0.0f, ay = 0.0f;
    for (; j + 1 < end; j += 2) {
        int s0 = esrc[j], s1 = esrc[j + 1];
        unsigned u0 = ((const unsigned*)(xb + (size_t)s0 * FDIM))[lane];
        unsigned u1 = ((const unsigned*)(xb + (size_t)s1 * FDIM))[lane];
        ax += bf_lo(u0) + bf_lo(u1);
        ay += bf_hi(u0) + bf_hi(u1);
    }
    if (j < end) {
        unsigned u = ((const unsigned*)(xb + (size_t)esrc[j] * FDIM))[lane];
        ax += bf_lo(u);
        ay += bf_hi(u);
    }
    float inv = 1.0f / fmaxf((float)c, 1.0f);
    unsigned o = (unsigned)f2bf(ax * inv) | ((unsigned)f2bf(ay * inv) << 16);
    ((unsigned*)(meanb + (size_t)seg * FDIM))[lane] = o;
}

// ---------- MFMA transform: out = [mean|x] @ Bsw + bias, relu ----------
// One wave per 32 rows, grid 3125 exact. Mean A-frags: direct 16B bf16 loads.
// x A-frags: f32 + packed cvt (x may be d_out; reads confined to own rows,
// writes after reads within the same wave). Writes f32 out AND bf16 sidecar.
__global__ __launch_bounds__(64) void rgcn_transform(
    const float* __restrict__ x,             // [N,128] f32
    const unsigned short* __restrict__ meanb,// [N,512] bf16
    const unsigned short* __restrict__ Bsw,  // this layer's [20][8][64][8]
    const float* __restrict__ bias,          // [128]
    float* __restrict__ out,                 // [N,128] f32
    unsigned short* __restrict__ xbn)        // [N,128] bf16 sidecar
{
    int lane = threadIdx.x;
    int quad = lane >> 4, rlo = lane & 15;
    int n0 = blockIdx.x * 32;
    int r0 = n0 + rlo;
    int r1 = n0 + 16 + rlo;

    const bfrag* m0 = (const bfrag*)(meanb + (size_t)r0 * 512) + quad;
    const bfrag* m1 = (const bfrag*)(meanb + (size_t)r1 * 512) + quad;
    const float* x0 = x + (size_t)r0 * FDIM + quad * 8;
    const float* x1 = x + (size_t)r1 * FDIM + quad * 8;
    const bfrag* bp = (const bfrag*)Bsw + lane;

    ffrag acc[2][8] = {};

    // k = 0..511 : mean part (row stride 512 bf16 = 64 bfrags; step 32 = 4 bfrags)
    #pragma unroll 4
    for (int kb = 0; kb < 16; ++kb) {
        bfrag a0 = m0[kb * 4];
        bfrag a1 = m1[kb * 4];
        #pragma unroll
        for (int ct = 0; ct < 8; ++ct) {
            bfrag b = bp[(kb * 8 + ct) * 64];
            acc[0][ct] = __builtin_amdgcn_mfma_f32_16x16x32_bf16(a0, b, acc[0][ct], 0, 0, 0);
            acc[1][ct] = __builtin_amdgcn_mfma_f32_16x16x32_bf16(a1, b, acc[1][ct], 0, 0, 0);
        }
    }
    // k = 512..639 : x part (f32 -> bf16 cvt in-register)
    #pragma unroll
    for (int kb = 0; kb < 4; ++kb) {
        bfrag a0 = cvt8(x0 + kb * 32);
        bfrag a1 = cvt8(x1 + kb * 32);
        #pragma unroll
        for (int ct = 0; ct < 8; ++ct) {
            bfrag b = bp[((16 + kb) * 8 + ct) * 64];
            acc[0][ct] = __builtin_amdgcn_mfma_f32_16x16x32_bf16(a0, b, acc[0][ct], 0, 0, 0);
            acc[1][ct] = __builtin_amdgcn_mfma_f32_16x16x32_bf16(a1, b, acc[1][ct], 0, 0, 0);
        }
    }

    // epilogue: D layout col = ct*16 + rlo, row = n0 + rt*16 + quad*4 + reg
    float bcol[8];
    #pragma unroll
    for (int ct = 0; ct < 8; ++ct) bcol[ct] = bias[ct * 16 + rlo];

    #pragma unroll
    for (int rt = 0; rt < 2; ++rt) {
        int rbase = n0 + rt * 16 + quad * 4;
        #pragma unroll
        for (int i = 0; i < 4; ++i) {
            int r = rbase + i;
            #pragma unroll
            for (int ct = 0; ct < 8; ++ct) {
                float v = fmaxf(acc[rt][ct][i] + bcol[ct], 0.0f);
                int col = ct * 16 + rlo;
                out[(size_t)r * FDIM + col] = v;
                xbn[(size_t)r * FDIM + col] = f2bf(v);
            }
        }
    }
}

extern "C" void kernel_launch(void* const* d_in, const int* in_sizes, int n_in,
                              void* d_out, int out_size, void* d_ws, size_t ws_size,
                              hipStream_t stream) {
    const float* x        = (const float*)d_in[0];
    const int* edge_index = (const int*)d_in[1]; // [2,E]
    const int* edge_type  = (const int*)d_in[2]; // [E]
    const float* weights  = (const float*)d_in[3]; // [L,R,F,F]
    const float* roots    = (const float*)d_in[4]; // [L,F,F]
    const float* biases   = (const float*)d_in[5]; // [L,F]
    float* out = (float*)d_out;

    // workspace layout
    unsigned short* meanb = (unsigned short*)d_ws;            // NSEG*128 bf16 = 102.4 MB
    unsigned short* xb0   = meanb + (size_t)NSEG * FDIM;      // N*128 bf16
    unsigned short* xb1   = xb0 + (size_t)N_NODES * FDIM;     // N*128 bf16
    unsigned short* Bsw   = xb1 + (size_t)N_NODES * FDIM;     // 2*81920 bf16
    int* esrc   = (int*)(Bsw + 2 * BSW_PER_LAYER);            // E ints
    int* counts = esrc + NEDGE;                               // NSEG
    int* cursor = counts + NSEG;                              // NSEG
    int* blockSums = cursor + NSEG;                           // 512

    const int* src = edge_index;
    const int* dst = edge_index + NEDGE;

    // prep: bf16 cast + weight swizzle + CSR (edges layer-invariant)
    cast_x<<<(N_NODES * FDIM / 4) / 256, 256, 0, stream>>>(x, xb0);
    prep_weights<<<2 * BSW_PER_LAYER / 256, 256, 0, stream>>>(weights, roots, Bsw);
    hipMemsetAsync(counts, 0, NSEG * sizeof(int), stream);
    count_edges<<<NEDGE / 256, 256, 0, stream>>>(dst, edge_type, counts);
    scan_blocks<<<SCAN_NB, 256, 0, stream>>>(counts, cursor, blockSums);
    scan_partials<<<1, 512, 0, stream>>>(blockSums);
    scan_add<<<SCAN_NB, 256, 0, stream>>>(cursor, blockSums);
    fill_edges<<<NEDGE / 256, 256, 0, stream>>>(src, dst, edge_type, cursor, esrc);

    // layer 1: gather bf16(x), transform -> d_out f32 + xb1 bf16 sidecar
    rgcn_aggregate<<<NSEG / 4, 256, 0, stream>>>(xb0, esrc, cursor, counts, meanb);
    rgcn_transform<<<N_NODES / 32, 64, 0, stream>>>(x, meanb, Bsw, biases, out, xb1);
    // layer 2: gather bf16 sidecar, transform -> d_out f32 (+ dead sidecar xb0)
    rgcn_aggregate<<<NSEG / 4, 256, 0, stream>>>(xb1, esrc, cursor, counts, meanb);
    rgcn_transform<<<N_NODES / 32, 64, 0, stream>>>(out, meanb, Bsw + BSW_PER_LAYER,
                                                    biases + FDIM, out, xb0);
}

// Round 6
// 600.650 us; speedup vs baseline: 10.2719x; 1.2473x over previous
//
#include <hip/hip_runtime.h>
#include <hip/hip_bf16.h>

// RGCN: N=100000, F=128, R=4, E=1600000, L=2.
// R6 = R5 with (a) aggregate restructured for 4x memory-level parallelism
// (16 lanes/segment, 4 segments/wave) and (b) transform reading bf16
// activations only (no f32 x reads, no in-loop cvt).
#define N_NODES 100000
#define FDIM 128
#define RREL 4
#define NEDGE 1600000
#define NSEG (N_NODES * RREL)          // 400000
#define SCAN_NB ((NSEG + 1023) / 1024) // 391
#define KB_TOT 20                      // 640 / 32 k-steps
#define BSW_PER_LAYER (KB_TOT * 8 * 64 * 8) // 81920 bf16 elems = 160 KB

typedef __attribute__((ext_vector_type(8))) short bfrag; // 8 bf16 (4 VGPR)
typedef __attribute__((ext_vector_type(4))) float ffrag; // 4 f32 acc

__device__ __forceinline__ unsigned short f2bf(float f) {
    unsigned u = __float_as_uint(f);
    u += 0x7fffu + ((u >> 16) & 1u); // RNE
    return (unsigned short)(u >> 16);
}
__device__ __forceinline__ float bf_lo(unsigned u) { return __uint_as_float(u << 16); }
__device__ __forceinline__ float bf_hi(unsigned u) { return __uint_as_float(u & 0xffff0000u); }

// ---------- cast x (f32) -> bf16 sidecar ----------
__global__ __launch_bounds__(256) void cast_x(
    const float* __restrict__ x, unsigned short* __restrict__ xb)
{
    int i = blockIdx.x * 256 + threadIdx.x; // one float4 per thread
    float4 v = ((const float4*)x)[i];
    ushort4 o = { f2bf(v.x), f2bf(v.y), f2bf(v.z), f2bf(v.w) };
    ((ushort4*)xb)[i] = o;
}

// ---------- pre-swizzle weights into MFMA B-fragment order ----------
// Bsw[layer][kb][ct][lane][j] = B[k = kb*32 + (lane>>4)*8 + j][n = ct*16 + (lane&15)]
__global__ __launch_bounds__(256) void prep_weights(
    const float* __restrict__ W,    // [L,4,128,128]
    const float* __restrict__ root, // [L,128,128]
    unsigned short* __restrict__ Bsw)
{
    int idx = blockIdx.x * 256 + threadIdx.x;
    int layer = idx / BSW_PER_LAYER;
    int rem = idx % BSW_PER_LAYER;
    int kb = rem / 4096;
    int rem2 = rem % 4096;
    int ct = rem2 / 512;
    int rem3 = rem2 % 512;
    int lane = rem3 / 8;
    int j = rem3 % 8;
    int k = kb * 32 + (lane >> 4) * 8 + j;
    int n = ct * 16 + (lane & 15);
    float v;
    if (k < 512) v = W[(size_t)layer * 4 * 128 * 128 + (size_t)k * 128 + n];
    else         v = root[(size_t)layer * 128 * 128 + (size_t)(k - 512) * 128 + n];
    Bsw[idx] = f2bf(v);
}

// ---------- CSR build (verbatim from R2/R4/R5) ----------
__global__ __launch_bounds__(256) void count_edges(
    const int* __restrict__ dst, const int* __restrict__ et,
    int* __restrict__ counts)
{
    int e = blockIdx.x * 256 + threadIdx.x;
    if (e < NEDGE) atomicAdd(&counts[dst[e] * RREL + et[e]], 1);
}

__global__ __launch_bounds__(256) void scan_blocks(
    const int* __restrict__ counts, int* __restrict__ cursor,
    int* __restrict__ blockSums)
{
    __shared__ int waveTot[4];
    int base = blockIdx.x * 1024 + threadIdx.x * 4;
    int v[4];
    #pragma unroll
    for (int i = 0; i < 4; ++i) {
        int idx = base + i;
        v[i] = (idx < NSEG) ? counts[idx] : 0;
    }
    int tsum = v[0] + v[1] + v[2] + v[3];
    int lane = threadIdx.x & 63;
    int wave = threadIdx.x >> 6;
    int inc = tsum;
    #pragma unroll
    for (int d = 1; d < 64; d <<= 1) {
        int o = __shfl_up(inc, d, 64);
        if (lane >= d) inc += o;
    }
    if (lane == 63) waveTot[wave] = inc;
    __syncthreads();
    int wbase = 0;
    for (int w = 0; w < wave; ++w) wbase += waveTot[w];
    int run = wbase + inc - tsum;
    #pragma unroll
    for (int i = 0; i < 4; ++i) {
        int idx = base + i;
        if (idx < NSEG) cursor[idx] = run;
        run += v[i];
    }
    if (threadIdx.x == 255) blockSums[blockIdx.x] = wbase + inc;
}

__global__ __launch_bounds__(512) void scan_partials(int* __restrict__ blockSums)
{
    __shared__ int sm[512];
    int t = threadIdx.x;
    int v = (t < SCAN_NB) ? blockSums[t] : 0;
    sm[t] = v;
    __syncthreads();
    for (int d = 1; d < 512; d <<= 1) {
        int o = (t >= d) ? sm[t - d] : 0;
        __syncthreads();
        sm[t] += o;
        __syncthreads();
    }
    if (t < SCAN_NB) blockSums[t] = sm[t] - v;
}

__global__ __launch_bounds__(256) void scan_add(
    int* __restrict__ cursor, const int* __restrict__ blockSums)
{
    int base = blockIdx.x * 1024 + threadIdx.x * 4;
    int add = blockSums[blockIdx.x];
    #pragma unroll
    for (int i = 0; i < 4; ++i)
        if (base + i < NSEG) cursor[base + i] += add;
}

__global__ __launch_bounds__(256) void fill_edges(
    const int* __restrict__ src, const int* __restrict__ dst,
    const int* __restrict__ et, int* __restrict__ cursor,
    int* __restrict__ esrc)
{
    int e = blockIdx.x * 256 + threadIdx.x;
    if (e < NEDGE) {
        int seg = dst[e] * RREL + et[e];
        int pos = atomicAdd(&cursor[seg], 1);
        esrc[pos] = src[e];
    }
}

// ---------- per-segment gather-reduce, 16 lanes/segment ----------
// Each 16-lane group owns one segment; lane holds 8 bf16 (uint4) of the row.
// 4 segments per wave x unroll 2 = up to 8 independent row-gathers in flight.
__global__ __launch_bounds__(256) void rgcn_aggregate(
    const unsigned short* __restrict__ xb, const int* __restrict__ esrc,
    const int* __restrict__ cursor, const int* __restrict__ counts,
    unsigned short* __restrict__ meanb)
{
    int sub = threadIdx.x >> 4;     // 0..15: segment within block
    int lane16 = threadIdx.x & 15;  // 16B chunk within row
    int seg = blockIdx.x * 16 + sub;
    int end = cursor[seg];
    int c = counts[seg];
    int j = end - c;
    float acc[8] = {};
    for (; j + 1 < end; j += 2) {
        int s0 = esrc[j], s1 = esrc[j + 1];
        uint4 u0 = ((const uint4*)(xb + (size_t)s0 * FDIM))[lane16];
        uint4 u1 = ((const uint4*)(xb + (size_t)s1 * FDIM))[lane16];
        acc[0] += bf_lo(u0.x) + bf_lo(u1.x);
        acc[1] += bf_hi(u0.x) + bf_hi(u1.x);
        acc[2] += bf_lo(u0.y) + bf_lo(u1.y);
        acc[3] += bf_hi(u0.y) + bf_hi(u1.y);
        acc[4] += bf_lo(u0.z) + bf_lo(u1.z);
        acc[5] += bf_hi(u0.z) + bf_hi(u1.z);
        acc[6] += bf_lo(u0.w) + bf_lo(u1.w);
        acc[7] += bf_hi(u0.w) + bf_hi(u1.w);
    }
    if (j < end) {
        int s = esrc[j];
        uint4 u = ((const uint4*)(xb + (size_t)s * FDIM))[lane16];
        acc[0] += bf_lo(u.x); acc[1] += bf_hi(u.x);
        acc[2] += bf_lo(u.y); acc[3] += bf_hi(u.y);
        acc[4] += bf_lo(u.z); acc[5] += bf_hi(u.z);
        acc[6] += bf_lo(u.w); acc[7] += bf_hi(u.w);
    }
    float inv = 1.0f / fmaxf((float)c, 1.0f);
    uint4 o;
    o.x = (unsigned)f2bf(acc[0] * inv) | ((unsigned)f2bf(acc[1] * inv) << 16);
    o.y = (unsigned)f2bf(acc[2] * inv) | ((unsigned)f2bf(acc[3] * inv) << 16);
    o.z = (unsigned)f2bf(acc[4] * inv) | ((unsigned)f2bf(acc[5] * inv) << 16);
    o.w = (unsigned)f2bf(acc[6] * inv) | ((unsigned)f2bf(acc[7] * inv) << 16);
    ((uint4*)(meanb + (size_t)seg * FDIM))[lane16] = o;
}

// ---------- MFMA transform: out = [mean|x] @ Bsw + bias, relu ----------
// One wave per 32 rows, grid 3125 exact. All A-frags are direct 16B bf16
// loads (mean + activation sidecar). Writes f32 out AND bf16 sidecar.
__global__ __launch_bounds__(64) void rgcn_transform(
    const unsigned short* __restrict__ xb,    // [N,128] bf16 activations
    const unsigned short* __restrict__ meanb, // [N,512] bf16
    const unsigned short* __restrict__ Bsw,   // this layer's [20][8][64][8]
    const float* __restrict__ bias,           // [128]
    float* __restrict__ out,                  // [N,128] f32
    unsigned short* __restrict__ xbn)         // [N,128] bf16 sidecar
{
    int lane = threadIdx.x;
    int quad = lane >> 4, rlo = lane & 15;
    int n0 = blockIdx.x * 32;
    int r0 = n0 + rlo;
    int r1 = n0 + 16 + rlo;

    const bfrag* m0 = (const bfrag*)(meanb + (size_t)r0 * 512) + quad;
    const bfrag* m1 = (const bfrag*)(meanb + (size_t)r1 * 512) + quad;
    const bfrag* x0 = (const bfrag*)(xb + (size_t)r0 * FDIM) + quad;
    const bfrag* x1 = (const bfrag*)(xb + (size_t)r1 * FDIM) + quad;
    const bfrag* bp = (const bfrag*)Bsw + lane;

    ffrag acc[2][8] = {};

    // k = 0..511 : mean part (row stride 512 bf16 = 64 bfrags; step 32 = 4)
    #pragma unroll 4
    for (int kb = 0; kb < 16; ++kb) {
        bfrag a0 = m0[kb * 4];
        bfrag a1 = m1[kb * 4];
        #pragma unroll
        for (int ct = 0; ct < 8; ++ct) {
            bfrag b = bp[(kb * 8 + ct) * 64];
            acc[0][ct] = __builtin_amdgcn_mfma_f32_16x16x32_bf16(a0, b, acc[0][ct], 0, 0, 0);
            acc[1][ct] = __builtin_amdgcn_mfma_f32_16x16x32_bf16(a1, b, acc[1][ct], 0, 0, 0);
        }
    }
    // k = 512..639 : x part (direct bf16 frags from sidecar)
    #pragma unroll
    for (int kb = 0; kb < 4; ++kb) {
        bfrag a0 = x0[kb * 4];
        bfrag a1 = x1[kb * 4];
        #pragma unroll
        for (int ct = 0; ct < 8; ++ct) {
            bfrag b = bp[((16 + kb) * 8 + ct) * 64];
            acc[0][ct] = __builtin_amdgcn_mfma_f32_16x16x32_bf16(a0, b, acc[0][ct], 0, 0, 0);
            acc[1][ct] = __builtin_amdgcn_mfma_f32_16x16x32_bf16(a1, b, acc[1][ct], 0, 0, 0);
        }
    }

    // epilogue: D layout col = ct*16 + rlo, row = n0 + rt*16 + quad*4 + reg
    float bcol[8];
    #pragma unroll
    for (int ct = 0; ct < 8; ++ct) bcol[ct] = bias[ct * 16 + rlo];

    #pragma unroll
    for (int rt = 0; rt < 2; ++rt) {
        int rbase = n0 + rt * 16 + quad * 4;
        #pragma unroll
        for (int i = 0; i < 4; ++i) {
            int r = rbase + i;
            #pragma unroll
            for (int ct = 0; ct < 8; ++ct) {
                float v = fmaxf(acc[rt][ct][i] + bcol[ct], 0.0f);
                int col = ct * 16 + rlo;
                out[(size_t)r * FDIM + col] = v;
                xbn[(size_t)r * FDIM + col] = f2bf(v);
            }
        }
    }
}

extern "C" void kernel_launch(void* const* d_in, const int* in_sizes, int n_in,
                              void* d_out, int out_size, void* d_ws, size_t ws_size,
                              hipStream_t stream) {
    const float* x        = (const float*)d_in[0];
    const int* edge_index = (const int*)d_in[1]; // [2,E]
    const int* edge_type  = (const int*)d_in[2]; // [E]
    const float* weights  = (const float*)d_in[3]; // [L,R,F,F]
    const float* roots    = (const float*)d_in[4]; // [L,F,F]
    const float* biases   = (const float*)d_in[5]; // [L,F]
    float* out = (float*)d_out;

    // workspace layout
    unsigned short* meanb = (unsigned short*)d_ws;            // NSEG*128 bf16 = 102.4 MB
    unsigned short* xb0   = meanb + (size_t)NSEG * FDIM;      // N*128 bf16
    unsigned short* xb1   = xb0 + (size_t)N_NODES * FDIM;     // N*128 bf16
    unsigned short* Bsw   = xb1 + (size_t)N_NODES * FDIM;     // 2*81920 bf16
    int* esrc   = (int*)(Bsw + 2 * BSW_PER_LAYER);            // E ints
    int* counts = esrc + NEDGE;                               // NSEG
    int* cursor = counts + NSEG;                              // NSEG
    int* blockSums = cursor + NSEG;                           // 512

    const int* src = edge_index;
    const int* dst = edge_index + NEDGE;

    // prep: bf16 cast + weight swizzle + CSR (edges layer-invariant)
    cast_x<<<(N_NODES * FDIM / 4) / 256, 256, 0, stream>>>(x, xb0);
    prep_weights<<<2 * BSW_PER_LAYER / 256, 256, 0, stream>>>(weights, roots, Bsw);
    hipMemsetAsync(counts, 0, NSEG * sizeof(int), stream);
    count_edges<<<NEDGE / 256, 256, 0, stream>>>(dst, edge_type, counts);
    scan_blocks<<<SCAN_NB, 256, 0, stream>>>(counts, cursor, blockSums);
    scan_partials<<<1, 512, 0, stream>>>(blockSums);
    scan_add<<<SCAN_NB, 256, 0, stream>>>(cursor, blockSums);
    fill_edges<<<NEDGE / 256, 256, 0, stream>>>(src, dst, edge_type, cursor, esrc);

    // layer 1
    rgcn_aggregate<<<NSEG / 16, 256, 0, stream>>>(xb0, esrc, cursor, counts, meanb);
    rgcn_transform<<<N_NODES / 32, 64, 0, stream>>>(xb0, meanb, Bsw, biases, out, xb1);
    // layer 2 (sidecar xb0 is dead output, kept for uniform work)
    rgcn_aggregate<<<NSEG / 16, 256, 0, stream>>>(xb1, esrc, cursor, counts, meanb);
    rgcn_transform<<<N_NODES / 32, 64, 0, stream>>>(xb1, meanb, Bsw + BSW_PER_LAYER,
                                                    biases + FDIM, out, xb0);
}

// Round 7
// 507.617 us; speedup vs baseline: 12.1544x; 1.1833x over previous
//
#include <hip/hip_runtime.h>
#include <hip/hip_bf16.h>

// RGCN: N=100000, F=128, R=4, E=1600000, L=2.
// R7 = R6 with transform restructured for latency: 256-thread blocks,
// double-buffered LDS staging of B tiles, depth-2 register pipeline on A,
// full K-loop unroll, launch_bounds(256,2). Everything else verbatim R6.
#define N_NODES 100000
#define FDIM 128
#define RREL 4
#define NEDGE 1600000
#define NSEG (N_NODES * RREL)          // 400000
#define SCAN_NB ((NSEG + 1023) / 1024) // 391
#define KB_TOT 20                      // 640 / 32 k-steps
#define BSW_PER_LAYER (KB_TOT * 8 * 64 * 8) // 81920 bf16 elems = 160 KB

typedef __attribute__((ext_vector_type(8))) short bfrag; // 8 bf16 (4 VGPR)
typedef __attribute__((ext_vector_type(4))) float ffrag; // 4 f32 acc

__device__ __forceinline__ unsigned short f2bf(float f) {
    unsigned u = __float_as_uint(f);
    u += 0x7fffu + ((u >> 16) & 1u); // RNE
    return (unsigned short)(u >> 16);
}
__device__ __forceinline__ float bf_lo(unsigned u) { return __uint_as_float(u << 16); }
__device__ __forceinline__ float bf_hi(unsigned u) { return __uint_as_float(u & 0xffff0000u); }

// ---------- cast x (f32) -> bf16 sidecar ----------
__global__ __launch_bounds__(256) void cast_x(
    const float* __restrict__ x, unsigned short* __restrict__ xb)
{
    int i = blockIdx.x * 256 + threadIdx.x; // one float4 per thread
    float4 v = ((const float4*)x)[i];
    ushort4 o = { f2bf(v.x), f2bf(v.y), f2bf(v.z), f2bf(v.w) };
    ((ushort4*)xb)[i] = o;
}

// ---------- pre-swizzle weights into MFMA B-fragment order ----------
// Bsw[layer][kb][ct][lane][j] = B[k = kb*32 + (lane>>4)*8 + j][n = ct*16 + (lane&15)]
__global__ __launch_bounds__(256) void prep_weights(
    const float* __restrict__ W,    // [L,4,128,128]
    const float* __restrict__ root, // [L,128,128]
    unsigned short* __restrict__ Bsw)
{
    int idx = blockIdx.x * 256 + threadIdx.x;
    int layer = idx / BSW_PER_LAYER;
    int rem = idx % BSW_PER_LAYER;
    int kb = rem / 4096;
    int rem2 = rem % 4096;
    int ct = rem2 / 512;
    int rem3 = rem2 % 512;
    int lane = rem3 / 8;
    int j = rem3 % 8;
    int k = kb * 32 + (lane >> 4) * 8 + j;
    int n = ct * 16 + (lane & 15);
    float v;
    if (k < 512) v = W[(size_t)layer * 4 * 128 * 128 + (size_t)k * 128 + n];
    else         v = root[(size_t)layer * 128 * 128 + (size_t)(k - 512) * 128 + n];
    Bsw[idx] = f2bf(v);
}

// ---------- CSR build (verbatim) ----------
__global__ __launch_bounds__(256) void count_edges(
    const int* __restrict__ dst, const int* __restrict__ et,
    int* __restrict__ counts)
{
    int e = blockIdx.x * 256 + threadIdx.x;
    if (e < NEDGE) atomicAdd(&counts[dst[e] * RREL + et[e]], 1);
}

__global__ __launch_bounds__(256) void scan_blocks(
    const int* __restrict__ counts, int* __restrict__ cursor,
    int* __restrict__ blockSums)
{
    __shared__ int waveTot[4];
    int base = blockIdx.x * 1024 + threadIdx.x * 4;
    int v[4];
    #pragma unroll
    for (int i = 0; i < 4; ++i) {
        int idx = base + i;
        v[i] = (idx < NSEG) ? counts[idx] : 0;
    }
    int tsum = v[0] + v[1] + v[2] + v[3];
    int lane = threadIdx.x & 63;
    int wave = threadIdx.x >> 6;
    int inc = tsum;
    #pragma unroll
    for (int d = 1; d < 64; d <<= 1) {
        int o = __shfl_up(inc, d, 64);
        if (lane >= d) inc += o;
    }
    if (lane == 63) waveTot[wave] = inc;
    __syncthreads();
    int wbase = 0;
    for (int w = 0; w < wave; ++w) wbase += waveTot[w];
    int run = wbase + inc - tsum;
    #pragma unroll
    for (int i = 0; i < 4; ++i) {
        int idx = base + i;
        if (idx < NSEG) cursor[idx] = run;
        run += v[i];
    }
    if (threadIdx.x == 255) blockSums[blockIdx.x] = wbase + inc;
}

__global__ __launch_bounds__(512) void scan_partials(int* __restrict__ blockSums)
{
    __shared__ int sm[512];
    int t = threadIdx.x;
    int v = (t < SCAN_NB) ? blockSums[t] : 0;
    sm[t] = v;
    __syncthreads();
    for (int d = 1; d < 512; d <<= 1) {
        int o = (t >= d) ? sm[t - d] : 0;
        __syncthreads();
        sm[t] += o;
        __syncthreads();
    }
    if (t < SCAN_NB) blockSums[t] = sm[t] - v;
}

__global__ __launch_bounds__(256) void scan_add(
    int* __restrict__ cursor, const int* __restrict__ blockSums)
{
    int base = blockIdx.x * 1024 + threadIdx.x * 4;
    int add = blockSums[blockIdx.x];
    #pragma unroll
    for (int i = 0; i < 4; ++i)
        if (base + i < NSEG) cursor[base + i] += add;
}

__global__ __launch_bounds__(256) void fill_edges(
    const int* __restrict__ src, const int* __restrict__ dst,
    const int* __restrict__ et, int* __restrict__ cursor,
    int* __restrict__ esrc)
{
    int e = blockIdx.x * 256 + threadIdx.x;
    if (e < NEDGE) {
        int seg = dst[e] * RREL + et[e];
        int pos = atomicAdd(&cursor[seg], 1);
        esrc[pos] = src[e];
    }
}

// ---------- per-segment gather-reduce, 16 lanes/segment (verbatim R6) ----------
__global__ __launch_bounds__(256) void rgcn_aggregate(
    const unsigned short* __restrict__ xb, const int* __restrict__ esrc,
    const int* __restrict__ cursor, const int* __restrict__ counts,
    unsigned short* __restrict__ meanb)
{
    int sub = threadIdx.x >> 4;
    int lane16 = threadIdx.x & 15;
    int seg = blockIdx.x * 16 + sub;
    int end = cursor[seg];
    int c = counts[seg];
    int j = end - c;
    float acc[8] = {};
    for (; j + 1 < end; j += 2) {
        int s0 = esrc[j], s1 = esrc[j + 1];
        uint4 u0 = ((const uint4*)(xb + (size_t)s0 * FDIM))[lane16];
        uint4 u1 = ((const uint4*)(xb + (size_t)s1 * FDIM))[lane16];
        acc[0] += bf_lo(u0.x) + bf_lo(u1.x);
        acc[1] += bf_hi(u0.x) + bf_hi(u1.x);
        acc[2] += bf_lo(u0.y) + bf_lo(u1.y);
        acc[3] += bf_hi(u0.y) + bf_hi(u1.y);
        acc[4] += bf_lo(u0.z) + bf_lo(u1.z);
        acc[5] += bf_hi(u0.z) + bf_hi(u1.z);
        acc[6] += bf_lo(u0.w) + bf_lo(u1.w);
        acc[7] += bf_hi(u0.w) + bf_hi(u1.w);
    }
    if (j < end) {
        int s = esrc[j];
        uint4 u = ((const uint4*)(xb + (size_t)s * FDIM))[lane16];
        acc[0] += bf_lo(u.x); acc[1] += bf_hi(u.x);
        acc[2] += bf_lo(u.y); acc[3] += bf_hi(u.y);
        acc[4] += bf_lo(u.z); acc[5] += bf_hi(u.z);
        acc[6] += bf_lo(u.w); acc[7] += bf_hi(u.w);
    }
    float inv = 1.0f / fmaxf((float)c, 1.0f);
    uint4 o;
    o.x = (unsigned)f2bf(acc[0] * inv) | ((unsigned)f2bf(acc[1] * inv) << 16);
    o.y = (unsigned)f2bf(acc[2] * inv) | ((unsigned)f2bf(acc[3] * inv) << 16);
    o.z = (unsigned)f2bf(acc[4] * inv) | ((unsigned)f2bf(acc[5] * inv) << 16);
    o.w = (unsigned)f2bf(acc[6] * inv) | ((unsigned)f2bf(acc[7] * inv) << 16);
    ((uint4*)(meanb + (size_t)seg * FDIM))[lane16] = o;
}

// ---------- MFMA transform, latency-restructured ----------
// Block = 256 threads = 4 waves; wave w covers rows n0 = blk*128 + w*32 .. +31.
// Per K-step (32 wide): B tile (8 KB) staged into double-buffered LDS by the
// whole block; each wave ds_reads its 8 B-frags. A-frags: depth-2 register
// pipeline over a fully unrolled K-loop. Grid 782 (rows clamped/guarded).
__global__ __launch_bounds__(256, 2) void rgcn_transform(
    const unsigned short* __restrict__ xb,    // [N,128] bf16 activations
    const unsigned short* __restrict__ meanb, // [N,512] bf16
    const unsigned short* __restrict__ Bsw,   // this layer's [20][8][64][8]
    const float* __restrict__ bias,           // [128]
    float* __restrict__ out,                  // [N,128] f32
    unsigned short* __restrict__ xbn)         // [N,128] bf16 sidecar
{
    __shared__ __align__(16) unsigned char Bsm[2][8192];

    int tid = threadIdx.x;
    int wave = tid >> 6, lane = tid & 63;
    int quad = lane >> 4, rlo = lane & 15;
    int n0 = blockIdx.x * 128 + wave * 32;
    int r0 = n0 + rlo;
    int r1 = n0 + 16 + rlo;
    int r0c = min(r0, N_NODES - 1);
    int r1c = min(r1, N_NODES - 1);

    const bfrag* m0 = (const bfrag*)(meanb + (size_t)r0c * 512) + quad;
    const bfrag* m1 = (const bfrag*)(meanb + (size_t)r1c * 512) + quad;
    const bfrag* x0 = (const bfrag*)(xb + (size_t)r0c * FDIM) + quad;
    const bfrag* x1 = (const bfrag*)(xb + (size_t)r1c * FDIM) + quad;

    // stage B tile kb into LDS buffer buf (8 KB, 512 uint4, 2 per thread)
    const uint4* gB = (const uint4*)Bsw;
    #define STAGE_B(kb, buf) do { \
        uint4* _s = (uint4*)Bsm[buf]; \
        const uint4* _g = gB + (kb) * 512; \
        _s[tid] = _g[tid]; \
        _s[tid + 256] = _g[tid + 256]; \
    } while (0)

    // A-frag for static kb (0..19): kb<16 -> mean, else x sidecar
    #define AFRAG(row, kb) ((kb) < 16 ? row##_m[(kb) * 4] : row##_x[((kb) - 16) * 4])
    const bfrag* r0_m = m0; const bfrag* r0_x = x0;
    const bfrag* r1_m = m1; const bfrag* r1_x = x1;

    ffrag acc[2][8] = {};

    STAGE_B(0, 0);
    // A pipeline, depth 2 (slots indexed kb&1 — static under full unroll)
    bfrag a0p0 = AFRAG(r0, 0), a1p0 = AFRAG(r1, 0);
    bfrag a0p1 = AFRAG(r0, 1), a1p1 = AFRAG(r1, 1);
    __syncthreads();

    #pragma unroll
    for (int kb = 0; kb < KB_TOT; ++kb) {
        int cur = kb & 1;
        if (kb + 1 < KB_TOT) STAGE_B(kb + 1, cur ^ 1);

        bfrag a0 = cur ? a0p1 : a0p0;
        bfrag a1 = cur ? a1p1 : a1p0;
        if (kb + 2 < KB_TOT) {
            if (cur) { a0p1 = AFRAG(r0, kb + 2); a1p1 = AFRAG(r1, kb + 2); }
            else     { a0p0 = AFRAG(r0, kb + 2); a1p0 = AFRAG(r1, kb + 2); }
        }

        #pragma unroll
        for (int ct = 0; ct < 8; ++ct) {
            bfrag b = *(const bfrag*)&Bsm[cur][ct * 1024 + lane * 16];
            acc[0][ct] = __builtin_amdgcn_mfma_f32_16x16x32_bf16(a0, b, acc[0][ct], 0, 0, 0);
            acc[1][ct] = __builtin_amdgcn_mfma_f32_16x16x32_bf16(a1, b, acc[1][ct], 0, 0, 0);
        }
        __syncthreads();
    }
    #undef STAGE_B
    #undef AFRAG

    // epilogue: D layout col = ct*16 + rlo, row = n0 + rt*16 + quad*4 + reg
    float bcol[8];
    #pragma unroll
    for (int ct = 0; ct < 8; ++ct) bcol[ct] = bias[ct * 16 + rlo];

    #pragma unroll
    for (int rt = 0; rt < 2; ++rt) {
        int rbase = n0 + rt * 16 + quad * 4;
        #pragma unroll
        for (int i = 0; i < 4; ++i) {
            int r = rbase + i;
            if (r < N_NODES) {
                #pragma unroll
                for (int ct = 0; ct < 8; ++ct) {
                    float v = fmaxf(acc[rt][ct][i] + bcol[ct], 0.0f);
                    int col = ct * 16 + rlo;
                    out[(size_t)r * FDIM + col] = v;
                    xbn[(size_t)r * FDIM + col] = f2bf(v);
                }
            }
        }
    }
}

extern "C" void kernel_launch(void* const* d_in, const int* in_sizes, int n_in,
                              void* d_out, int out_size, void* d_ws, size_t ws_size,
                              hipStream_t stream) {
    const float* x        = (const float*)d_in[0];
    const int* edge_index = (const int*)d_in[1]; // [2,E]
    const int* edge_type  = (const int*)d_in[2]; // [E]
    const float* weights  = (const float*)d_in[3]; // [L,R,F,F]
    const float* roots    = (const float*)d_in[4]; // [L,F,F]
    const float* biases   = (const float*)d_in[5]; // [L,F]
    float* out = (float*)d_out;

    // workspace layout
    unsigned short* meanb = (unsigned short*)d_ws;            // NSEG*128 bf16 = 102.4 MB
    unsigned short* xb0   = meanb + (size_t)NSEG * FDIM;      // N*128 bf16
    unsigned short* xb1   = xb0 + (size_t)N_NODES * FDIM;     // N*128 bf16
    unsigned short* Bsw   = xb1 + (size_t)N_NODES * FDIM;     // 2*81920 bf16
    int* esrc   = (int*)(Bsw + 2 * BSW_PER_LAYER);            // E ints
    int* counts = esrc + NEDGE;                               // NSEG
    int* cursor = counts + NSEG;                              // NSEG
    int* blockSums = cursor + NSEG;                           // 512

    const int* src = edge_index;
    const int* dst = edge_index + NEDGE;

    // prep: bf16 cast + weight swizzle + CSR (edges layer-invariant)
    cast_x<<<(N_NODES * FDIM / 4) / 256, 256, 0, stream>>>(x, xb0);
    prep_weights<<<2 * BSW_PER_LAYER / 256, 256, 0, stream>>>(weights, roots, Bsw);
    hipMemsetAsync(counts, 0, NSEG * sizeof(int), stream);
    count_edges<<<NEDGE / 256, 256, 0, stream>>>(dst, edge_type, counts);
    scan_blocks<<<SCAN_NB, 256, 0, stream>>>(counts, cursor, blockSums);
    scan_partials<<<1, 512, 0, stream>>>(blockSums);
    scan_add<<<SCAN_NB, 256, 0, stream>>>(cursor, blockSums);
    fill_edges<<<NEDGE / 256, 256, 0, stream>>>(src, dst, edge_type, cursor, esrc);

    const int tgrid = (N_NODES + 127) / 128; // 782

    // layer 1
    rgcn_aggregate<<<NSEG / 16, 256, 0, stream>>>(xb0, esrc, cursor, counts, meanb);
    rgcn_transform<<<tgrid, 256, 0, stream>>>(xb0, meanb, Bsw, biases, out, xb1);
    // layer 2 (sidecar xb0 is dead output, kept for uniform work)
    rgcn_aggregate<<<NSEG / 16, 256, 0, stream>>>(xb1, esrc, cursor, counts, meanb);
    rgcn_transform<<<tgrid, 256, 0, stream>>>(xb1, meanb, Bsw + BSW_PER_LAYER,
                                              biases + FDIM, out, xb0);
}